// Round 1
// baseline (5970.118 us; speedup 1.0000x reference)
//
#include <hip/hip_runtime.h>
#include <math.h>

#define D 512
#define NH 8
#define DHEAD 64
#define LAYERS 6
#define DFF 2048
#define BATCH 8
#define SEQ 128
#define ROWS (BATCH * SEQ)   // 1024

// ---------------- embedding + positional encoding ----------------
// out[bs, d] = emb[tok[bs], d] * sqrt(D) + pe(s, d)
__global__ __launch_bounds__(256) void embed_pe_kernel(const int* __restrict__ tok,
        const float* __restrict__ emb, float* __restrict__ out)
{
    int i = blockIdx.x * 256 + threadIdx.x;       // 0 .. ROWS*D-1 (exact grid)
    int bs = i >> 9;                              // row (b*SEQ + s)
    int d  = i & 511;
    int s  = bs & (SEQ - 1);
    int tk = tok[bs];
    // div = exp(-(d & ~1) * ln(10000)/512); even -> sin, odd -> cos
    float dv  = expf(-(float)(d & ~1) * (9.210340371976184f / 512.0f));
    float arg = (float)s * dv;
    float pe  = (d & 1) ? cosf(arg) : sinf(arg);
    out[i] = emb[(size_t)tk * D + d] * 22.627416997969522f + pe;
}

// ---------------- LayerNorm: one wave per row of 512 ----------------
__global__ __launch_bounds__(256) void ln_kernel(const float* __restrict__ x,
        const float* __restrict__ g, const float* __restrict__ bta,
        float* __restrict__ out)
{
    int lane = threadIdx.x & 63;
    int row  = (blockIdx.x << 2) + (threadIdx.x >> 6);
    const float* xr = x + (size_t)row * D;
    int c = lane * 8;
    float4 v0 = *(const float4*)(xr + c);
    float4 v1 = *(const float4*)(xr + c + 4);
    float s  = v0.x + v0.y + v0.z + v0.w + v1.x + v1.y + v1.z + v1.w;
    float sq = v0.x*v0.x + v0.y*v0.y + v0.z*v0.z + v0.w*v0.w
             + v1.x*v1.x + v1.y*v1.y + v1.z*v1.z + v1.w*v1.w;
    #pragma unroll
    for (int o = 32; o; o >>= 1) {
        s  += __shfl_xor(s, o);
        sq += __shfl_xor(sq, o);
    }
    float mean = s * (1.0f / D);
    float var  = sq * (1.0f / D) - mean * mean;
    float inv  = rsqrtf(var + 1e-6f);
    float4 g0 = *(const float4*)(g + c),   g1 = *(const float4*)(g + c + 4);
    float4 b0 = *(const float4*)(bta + c), b1 = *(const float4*)(bta + c + 4);
    float4 o0, o1;
    o0.x = g0.x * (v0.x - mean) * inv + b0.x;
    o0.y = g0.y * (v0.y - mean) * inv + b0.y;
    o0.z = g0.z * (v0.z - mean) * inv + b0.z;
    o0.w = g0.w * (v0.w - mean) * inv + b0.w;
    o1.x = g1.x * (v1.x - mean) * inv + b1.x;
    o1.y = g1.y * (v1.y - mean) * inv + b1.y;
    o1.z = g1.z * (v1.z - mean) * inv + b1.z;
    o1.w = g1.w * (v1.w - mean) * inv + b1.w;
    *(float4*)(out + (size_t)row * D + c)     = o0;
    *(float4*)(out + (size_t)row * D + c + 4) = o1;
}

// ---------------- fp32 tiled GEMM: C = A[M,K] @ W[K,N] + bias (+R) (+relu) ----
// 64x64 tile, BK=16, 256 threads, 4x4 per thread.
template<int RESID, int RELU>
__global__ __launch_bounds__(256) void gemm_kernel(
        const float* __restrict__ A, const float* __restrict__ W,
        const float* __restrict__ bias, const float* __restrict__ R,
        float* __restrict__ C, int M, int N, int Kd)
{
    __shared__ float As[16][64];
    __shared__ float Bs[16][64];
    const int tid = threadIdx.x;
    const int tx = tid & 15, ty = tid >> 4;
    const int bm = blockIdx.y << 6, bn = blockIdx.x << 6;
    const int am = tid >> 2, ac = (tid & 3) << 2;    // A tile: row am, 4-col group ac
    const int br = tid >> 4, bc = (tid & 15) << 2;   // B tile: row br, 4-col group bc
    float acc[4][4] = {};
    for (int k0 = 0; k0 < Kd; k0 += 16) {
        float4 a4 = *(const float4*)(A + (size_t)(bm + am) * Kd + k0 + ac);
        float4 b4 = *(const float4*)(W + (size_t)(k0 + br) * N + bn + bc);
        As[ac + 0][am] = a4.x;
        As[ac + 1][am] = a4.y;
        As[ac + 2][am] = a4.z;
        As[ac + 3][am] = a4.w;
        *(float4*)&Bs[br][bc] = b4;
        __syncthreads();
        #pragma unroll
        for (int kk = 0; kk < 16; ++kk) {
            float a0 = As[kk][(ty << 2) + 0];
            float a1 = As[kk][(ty << 2) + 1];
            float a2 = As[kk][(ty << 2) + 2];
            float a3 = As[kk][(ty << 2) + 3];
            float4 bv = *(const float4*)&Bs[kk][tx << 2];
            acc[0][0] += a0 * bv.x; acc[0][1] += a0 * bv.y; acc[0][2] += a0 * bv.z; acc[0][3] += a0 * bv.w;
            acc[1][0] += a1 * bv.x; acc[1][1] += a1 * bv.y; acc[1][2] += a1 * bv.z; acc[1][3] += a1 * bv.w;
            acc[2][0] += a2 * bv.x; acc[2][1] += a2 * bv.y; acc[2][2] += a2 * bv.z; acc[2][3] += a2 * bv.w;
            acc[3][0] += a3 * bv.x; acc[3][1] += a3 * bv.y; acc[3][2] += a3 * bv.z; acc[3][3] += a3 * bv.w;
        }
        __syncthreads();
    }
    const int m0 = bm + (ty << 2), n0 = bn + (tx << 2);
    float4 bias4 = *(const float4*)(bias + n0);
    #pragma unroll
    for (int i = 0; i < 4; ++i) {
        int m = m0 + i;
        float4 o;
        o.x = acc[i][0] + bias4.x;
        o.y = acc[i][1] + bias4.y;
        o.z = acc[i][2] + bias4.z;
        o.w = acc[i][3] + bias4.w;
        if (RESID) {
            float4 r4 = *(const float4*)(R + (size_t)m * N + n0);
            o.x += r4.x; o.y += r4.y; o.z += r4.z; o.w += r4.w;
        }
        if (RELU) {
            o.x = fmaxf(o.x, 0.f); o.y = fmaxf(o.y, 0.f);
            o.z = fmaxf(o.z, 0.f); o.w = fmaxf(o.w, 0.f);
        }
        *(float4*)(C + (size_t)m * N + n0) = o;
    }
}

// ---------------- fused attention, one block per (b, h) -------------------
// Q,K,V,O all laid out [b, s, D] with head slice at column h*64. Online softmax,
// one query row per thread, K/V staged in LDS (64 KB).
template<int CAUSAL>
__global__ __launch_bounds__(128) void attn_kernel(
        const float* __restrict__ Qb, const float* __restrict__ Kb,
        const float* __restrict__ Vb, float* __restrict__ Ob)
{
    __shared__ float Ks[SEQ][DHEAD];
    __shared__ float Vs[SEQ][DHEAD];
    const int bh = blockIdx.x;
    const size_t base = ((size_t)(bh >> 3) * SEQ) * D + (size_t)(bh & 7) * DHEAD;
    const int t = threadIdx.x;
    #pragma unroll
    for (int it = 0; it < 16; ++it) {
        int idx  = it * 128 + t;
        int srow = idx >> 4;
        int j4   = (idx & 15) << 2;
        *(float4*)&Ks[srow][j4] = *(const float4*)(Kb + base + (size_t)srow * D + j4);
        *(float4*)&Vs[srow][j4] = *(const float4*)(Vb + base + (size_t)srow * D + j4);
    }
    __syncthreads();
    float q[DHEAD];
    const float* qp = Qb + base + (size_t)t * D;
    #pragma unroll
    for (int j4 = 0; j4 < 16; ++j4) {
        float4 v = *(const float4*)(qp + (j4 << 2));
        q[j4 * 4 + 0] = v.x; q[j4 * 4 + 1] = v.y;
        q[j4 * 4 + 2] = v.z; q[j4 * 4 + 3] = v.w;
    }
    float m = -INFINITY, l = 0.f;
    float acc[DHEAD];
    #pragma unroll
    for (int j = 0; j < DHEAD; ++j) acc[j] = 0.f;
    const int kend = CAUSAL ? (t + 1) : SEQ;
    for (int k = 0; k < kend; ++k) {
        float s = 0.f;
        const float4* kr = (const float4*)&Ks[k][0];
        #pragma unroll
        for (int j4 = 0; j4 < 16; ++j4) {
            float4 kv = kr[j4];
            s += q[j4*4+0]*kv.x + q[j4*4+1]*kv.y + q[j4*4+2]*kv.z + q[j4*4+3]*kv.w;
        }
        s *= 0.125f;  // 1/sqrt(64)
        float nm = fmaxf(m, s);
        float f = __expf(m - nm);   // first iter: m=-inf -> f=0
        float p = __expf(s - nm);
        l = l * f + p;
        const float4* vr = (const float4*)&Vs[k][0];
        #pragma unroll
        for (int j4 = 0; j4 < 16; ++j4) {
            float4 vv = vr[j4];
            acc[j4*4+0] = acc[j4*4+0] * f + p * vv.x;
            acc[j4*4+1] = acc[j4*4+1] * f + p * vv.y;
            acc[j4*4+2] = acc[j4*4+2] * f + p * vv.z;
            acc[j4*4+3] = acc[j4*4+3] * f + p * vv.w;
        }
        m = nm;
    }
    float invl = 1.f / l;
    float* op = Ob + base + (size_t)t * D;
    #pragma unroll
    for (int j4 = 0; j4 < 16; ++j4) {
        float4 o;
        o.x = acc[j4*4+0] * invl; o.y = acc[j4*4+1] * invl;
        o.z = acc[j4*4+2] * invl; o.w = acc[j4*4+3] * invl;
        *(float4*)(op + (j4 << 2)) = o;
    }
}

// ------------------------------------------------------------------------
static inline void launch_gemm(const float* A, const float* W, const float* bias,
        const float* R, float* C, int M, int N, int Kd, int relu, hipStream_t stream)
{
    dim3 grid(N / 64, M / 64), blk(256);
    if (R)          gemm_kernel<1, 0><<<grid, blk, 0, stream>>>(A, W, bias, R, C, M, N, Kd);
    else if (relu)  gemm_kernel<0, 1><<<grid, blk, 0, stream>>>(A, W, bias, nullptr, C, M, N, Kd);
    else            gemm_kernel<0, 0><<<grid, blk, 0, stream>>>(A, W, bias, nullptr, C, M, N, Kd);
}

static inline void launch_ln(const float* x, const float* g, const float* b,
        float* out, hipStream_t stream)
{
    ln_kernel<<<dim3(ROWS / 4), dim3(256), 0, stream>>>(x, g, b, out);
}

extern "C" void kernel_launch(void* const* d_in, const int* in_sizes, int n_in,
                              void* d_out, int out_size, void* d_ws, size_t ws_size,
                              hipStream_t stream)
{
    const int*   src       = (const int*)d_in[0];
    const int*   tgt       = (const int*)d_in[1];
    const float* src_emb   = (const float*)d_in[2];
    const float* tgt_emb   = (const float*)d_in[3];
    const float* enc_qkv_w = (const float*)d_in[4];
    const float* enc_qkv_b = (const float*)d_in[5];
    const float* enc_o_w   = (const float*)d_in[6];
    const float* enc_o_b   = (const float*)d_in[7];
    const float* enc_ff_w1 = (const float*)d_in[8];
    const float* enc_ff_b1 = (const float*)d_in[9];
    const float* enc_ff_w2 = (const float*)d_in[10];
    const float* enc_ff_b2 = (const float*)d_in[11];
    const float* enc_ln_g  = (const float*)d_in[12];
    const float* enc_ln_b  = (const float*)d_in[13];
    const float* enc_fg    = (const float*)d_in[14];
    const float* enc_fb    = (const float*)d_in[15];
    const float* dec_sqkv_w = (const float*)d_in[16];
    const float* dec_sqkv_b = (const float*)d_in[17];
    const float* dec_so_w   = (const float*)d_in[18];
    const float* dec_so_b   = (const float*)d_in[19];
    const float* dec_cqkv_w = (const float*)d_in[20];
    const float* dec_cqkv_b = (const float*)d_in[21];
    const float* dec_co_w   = (const float*)d_in[22];
    const float* dec_co_b   = (const float*)d_in[23];
    const float* dec_ff_w1  = (const float*)d_in[24];
    const float* dec_ff_b1  = (const float*)d_in[25];
    const float* dec_ff_w2  = (const float*)d_in[26];
    const float* dec_ff_b2  = (const float*)d_in[27];
    const float* dec_ln_g   = (const float*)d_in[28];
    const float* dec_ln_b   = (const float*)d_in[29];
    const float* dec_fg     = (const float*)d_in[30];
    const float* dec_fb     = (const float*)d_in[31];

    float* ws  = (float*)d_ws;
    float* X   = ws;                  // [1024, 512] residual stream
    float* H   = X  + ROWS * D;       // [1024, 512] LN output
    float* Qb  = H  + ROWS * D;
    float* Kb  = Qb + ROWS * D;
    float* Vb  = Kb + ROWS * D;
    float* ATT = Vb + ROWS * D;
    float* MEM = ATT + ROWS * D;
    float* F1  = MEM + ROWS * D;      // [1024, 2048]

    // ---------------- encoder ----------------
    embed_pe_kernel<<<dim3(ROWS * D / 256), dim3(256), 0, stream>>>(src, src_emb, X);
    for (int i = 0; i < LAYERS; ++i) {
        const float* qkvw = enc_qkv_w + (size_t)i * 3 * D * D;
        const float* qkvb = enc_qkv_b + (size_t)i * 3 * D;
        launch_ln(X, enc_ln_g + (size_t)(i * 2 + 0) * D, enc_ln_b + (size_t)(i * 2 + 0) * D, H, stream);
        launch_gemm(H, qkvw + 0 * D * D, qkvb + 0 * D, nullptr, Qb, ROWS, D, D, 0, stream);
        launch_gemm(H, qkvw + 1 * D * D, qkvb + 1 * D, nullptr, Kb, ROWS, D, D, 0, stream);
        launch_gemm(H, qkvw + 2 * D * D, qkvb + 2 * D, nullptr, Vb, ROWS, D, D, 0, stream);
        attn_kernel<0><<<dim3(BATCH * NH), dim3(128), 0, stream>>>(Qb, Kb, Vb, ATT);
        launch_gemm(ATT, enc_o_w + (size_t)i * D * D, enc_o_b + (size_t)i * D, X, X, ROWS, D, D, 0, stream);
        launch_ln(X, enc_ln_g + (size_t)(i * 2 + 1) * D, enc_ln_b + (size_t)(i * 2 + 1) * D, H, stream);
        launch_gemm(H, enc_ff_w1 + (size_t)i * D * DFF, enc_ff_b1 + (size_t)i * DFF, nullptr, F1, ROWS, DFF, D, 1, stream);
        launch_gemm(F1, enc_ff_w2 + (size_t)i * DFF * D, enc_ff_b2 + (size_t)i * D, X, X, ROWS, D, DFF, 0, stream);
    }
    launch_ln(X, enc_fg, enc_fb, MEM, stream);

    // ---------------- decoder ----------------
    embed_pe_kernel<<<dim3(ROWS * D / 256), dim3(256), 0, stream>>>(tgt, tgt_emb, X);
    for (int i = 0; i < LAYERS; ++i) {
        // self-attention (causal)
        const float* sqkvw = dec_sqkv_w + (size_t)i * 3 * D * D;
        const float* sqkvb = dec_sqkv_b + (size_t)i * 3 * D;
        launch_ln(X, dec_ln_g + (size_t)(i * 3 + 0) * D, dec_ln_b + (size_t)(i * 3 + 0) * D, H, stream);
        launch_gemm(H, sqkvw + 0 * D * D, sqkvb + 0 * D, nullptr, Qb, ROWS, D, D, 0, stream);
        launch_gemm(H, sqkvw + 1 * D * D, sqkvb + 1 * D, nullptr, Kb, ROWS, D, D, 0, stream);
        launch_gemm(H, sqkvw + 2 * D * D, sqkvb + 2 * D, nullptr, Vb, ROWS, D, D, 0, stream);
        attn_kernel<1><<<dim3(BATCH * NH), dim3(128), 0, stream>>>(Qb, Kb, Vb, ATT);
        launch_gemm(ATT, dec_so_w + (size_t)i * D * D, dec_so_b + (size_t)i * D, X, X, ROWS, D, D, 0, stream);
        // cross-attention (q from decoder stream, k/v from encoder memory)
        const float* cqkvw = dec_cqkv_w + (size_t)i * 3 * D * D;
        const float* cqkvb = dec_cqkv_b + (size_t)i * 3 * D;
        launch_ln(X, dec_ln_g + (size_t)(i * 3 + 1) * D, dec_ln_b + (size_t)(i * 3 + 1) * D, H, stream);
        launch_gemm(H,   cqkvw + 0 * D * D, cqkvb + 0 * D, nullptr, Qb, ROWS, D, D, 0, stream);
        launch_gemm(MEM, cqkvw + 1 * D * D, cqkvb + 1 * D, nullptr, Kb, ROWS, D, D, 0, stream);
        launch_gemm(MEM, cqkvw + 2 * D * D, cqkvb + 2 * D, nullptr, Vb, ROWS, D, D, 0, stream);
        attn_kernel<0><<<dim3(BATCH * NH), dim3(128), 0, stream>>>(Qb, Kb, Vb, ATT);
        launch_gemm(ATT, dec_co_w + (size_t)i * D * D, dec_co_b + (size_t)i * D, X, X, ROWS, D, D, 0, stream);
        // feed-forward
        launch_ln(X, dec_ln_g + (size_t)(i * 3 + 2) * D, dec_ln_b + (size_t)(i * 3 + 2) * D, H, stream);
        launch_gemm(H, dec_ff_w1 + (size_t)i * D * DFF, dec_ff_b1 + (size_t)i * DFF, nullptr, F1, ROWS, DFF, D, 1, stream);
        launch_gemm(F1, dec_ff_w2 + (size_t)i * DFF * D, dec_ff_b2 + (size_t)i * D, X, X, ROWS, D, DFF, 0, stream);
    }
    launch_ln(X, dec_fg, dec_fb, (float*)d_out, stream);
}

// Round 2
// 3438.264 us; speedup vs baseline: 1.7364x; 1.7364x over previous
//
#include <hip/hip_runtime.h>
#include <hip/hip_bf16.h>
#include <math.h>

#define D 512
#define NH 8
#define DHEAD 64
#define LAYERS 6
#define DFF 2048
#define BATCH 8
#define SEQ 128
#define ROWS (BATCH * SEQ)   // 1024

typedef float f32x4 __attribute__((ext_vector_type(4)));
typedef short bf16x8 __attribute__((ext_vector_type(8)));

__device__ __forceinline__ unsigned short f2b(float x) {
    return __builtin_bit_cast(unsigned short, __float2bfloat16(x));
}
__device__ __forceinline__ float b2f(unsigned int u) {
    return __builtin_bit_cast(float, u << 16);   // uses low 16 bits of u
}
__device__ __forceinline__ void unp8(uint4 u, float* d) {
    d[0] = b2f(u.x); d[1] = b2f(u.x >> 16);
    d[2] = b2f(u.y); d[3] = b2f(u.y >> 16);
    d[4] = b2f(u.z); d[5] = b2f(u.z >> 16);
    d[6] = b2f(u.w); d[7] = b2f(u.w >> 16);
}

// ---------------- embedding + positional encoding (fp32 out) ----------------
__global__ __launch_bounds__(256) void embed_pe_kernel(const int* __restrict__ tok,
        const float* __restrict__ emb, float* __restrict__ out)
{
    int i = blockIdx.x * 256 + threadIdx.x;
    int bs = i >> 9;
    int d  = i & 511;
    int s  = bs & (SEQ - 1);
    int tk = tok[bs];
    float dv  = expf(-(float)(d & ~1) * (9.210340371976184f / 512.0f));
    float arg = (float)s * dv;
    float pe  = (d & 1) ? cosf(arg) : sinf(arg);
    out[i] = emb[(size_t)tk * D + d] * 22.627416997969522f + pe;
}

// ---------------- batched transpose + fp32->bf16 convert --------------------
// in: nMat matrices [R][C] fp32 ; out: [C][R] bf16 at the same flat offset.
__global__ __launch_bounds__(256) void transpose_cvt_kernel(
        const float* __restrict__ in, unsigned short* __restrict__ out, int R, int C)
{
    __shared__ float t[32][33];
    const size_t moff = (size_t)blockIdx.z * R * C;
    const float* src = in + moff;
    unsigned short* dst = out + moff;
    const int r0 = blockIdx.y << 5, c0 = blockIdx.x << 5;
    const int tid = threadIdx.x;
    const int rr = tid >> 3, cc = (tid & 7) << 2;
    float4 v = *(const float4*)(src + (size_t)(r0 + rr) * C + c0 + cc);
    t[rr][cc] = v.x; t[rr][cc + 1] = v.y; t[rr][cc + 2] = v.z; t[rr][cc + 3] = v.w;
    __syncthreads();
    const int oc = tid >> 3, or4 = (tid & 7) << 2;
    ushort4 o;
    o.x = f2b(t[or4 + 0][oc]);
    o.y = f2b(t[or4 + 1][oc]);
    o.z = f2b(t[or4 + 2][oc]);
    o.w = f2b(t[or4 + 3][oc]);
    *(ushort4*)(dst + (size_t)(c0 + oc) * R + r0 + or4) = o;
}

// ---------------- LayerNorm: one wave per row of 512 ------------------------
template<int OUT_BF16>
__global__ __launch_bounds__(256) void ln_kernel(const float* __restrict__ x,
        const float* __restrict__ g, const float* __restrict__ bta,
        void* __restrict__ outp)
{
    int lane = threadIdx.x & 63;
    int row  = (blockIdx.x << 2) + (threadIdx.x >> 6);
    const float* xr = x + (size_t)row * D;
    int c = lane * 8;
    float4 v0 = *(const float4*)(xr + c);
    float4 v1 = *(const float4*)(xr + c + 4);
    float s  = v0.x + v0.y + v0.z + v0.w + v1.x + v1.y + v1.z + v1.w;
    float sq = v0.x*v0.x + v0.y*v0.y + v0.z*v0.z + v0.w*v0.w
             + v1.x*v1.x + v1.y*v1.y + v1.z*v1.z + v1.w*v1.w;
    #pragma unroll
    for (int o = 32; o; o >>= 1) {
        s  += __shfl_xor(s, o);
        sq += __shfl_xor(sq, o);
    }
    float mean = s * (1.0f / D);
    float var  = sq * (1.0f / D) - mean * mean;
    float inv  = rsqrtf(var + 1e-6f);
    float4 g0 = *(const float4*)(g + c),   g1 = *(const float4*)(g + c + 4);
    float4 b0 = *(const float4*)(bta + c), b1 = *(const float4*)(bta + c + 4);
    float4 o0, o1;
    o0.x = g0.x * (v0.x - mean) * inv + b0.x;
    o0.y = g0.y * (v0.y - mean) * inv + b0.y;
    o0.z = g0.z * (v0.z - mean) * inv + b0.z;
    o0.w = g0.w * (v0.w - mean) * inv + b0.w;
    o1.x = g1.x * (v1.x - mean) * inv + b1.x;
    o1.y = g1.y * (v1.y - mean) * inv + b1.y;
    o1.z = g1.z * (v1.z - mean) * inv + b1.z;
    o1.w = g1.w * (v1.w - mean) * inv + b1.w;
    if (OUT_BF16) {
        unsigned short* orow = (unsigned short*)outp + (size_t)row * D + c;
        uint4 o;
        o.x = (unsigned int)f2b(o0.x) | ((unsigned int)f2b(o0.y) << 16);
        o.y = (unsigned int)f2b(o0.z) | ((unsigned int)f2b(o0.w) << 16);
        o.z = (unsigned int)f2b(o1.x) | ((unsigned int)f2b(o1.y) << 16);
        o.w = (unsigned int)f2b(o1.z) | ((unsigned int)f2b(o1.w) << 16);
        *(uint4*)orow = o;
    } else {
        float* orow = (float*)outp + (size_t)row * D + c;
        *(float4*)(orow)     = o0;
        *(float4*)(orow + 4) = o1;
    }
}

// ---------------- bf16 MFMA GEMM: C = A[M,K] @ Wt[N,K]^T + bias -------------
// BM=BN=64, BK=32, 256 threads = 4 waves in 2x2; each wave 2x2 frags of
// 16x16x32. A and Wt are both row-major K-contiguous bf16.
// M is always 1024 (grid.y = 16).
template<int RESID, int RELU, int OUT_BF16>
__global__ __launch_bounds__(256) void mgemm_kernel(
        const unsigned short* __restrict__ A,   // bf16 [1024][K]
        const unsigned short* __restrict__ Wt,  // bf16 [N][K]
        const float* __restrict__ bias,         // fp32 [N]
        const float* __restrict__ Rp,           // fp32 [1024][N] residual
        void* __restrict__ Cout,                // bf16 or fp32 [1024][N]
        int N, int K)
{
    __shared__ unsigned short As[64][40];   // pad 32->40 (80B row stride)
    __shared__ unsigned short Bs[64][40];
    const int tid  = threadIdx.x;
    const int lane = tid & 63, wid = tid >> 6;
    const int wm = wid >> 1, wn = wid & 1;
    const int bm = blockIdx.y << 6, bn = blockIdx.x << 6;
    const int srow = tid >> 2, sk = (tid & 3) << 3;   // staging: 16B per thread
    const unsigned short* Ag = A  + (size_t)(bm + srow) * K + sk;
    const unsigned short* Bg = Wt + (size_t)(bn + srow) * K + sk;
    const int fr = lane & 15;           // fragment row (M or N index)
    const int fk = (lane >> 4) << 3;    // fragment k offset: 0/8/16/24
    f32x4 acc[2][2];
    #pragma unroll
    for (int i = 0; i < 2; ++i)
        #pragma unroll
        for (int j = 0; j < 2; ++j)
            acc[i][j] = (f32x4){0.f, 0.f, 0.f, 0.f};
    for (int k0 = 0; k0 < K; k0 += 32) {
        uint4 av = *(const uint4*)Ag;
        uint4 bv = *(const uint4*)Bg;
        Ag += 32; Bg += 32;
        __syncthreads();                 // previous compute done reading LDS
        *(uint4*)&As[srow][sk] = av;
        *(uint4*)&Bs[srow][sk] = bv;
        __syncthreads();
        bf16x8 af0 = *(const bf16x8*)&As[wm * 32 + fr][fk];
        bf16x8 af1 = *(const bf16x8*)&As[wm * 32 + 16 + fr][fk];
        bf16x8 bf0 = *(const bf16x8*)&Bs[wn * 32 + fr][fk];
        bf16x8 bf1 = *(const bf16x8*)&Bs[wn * 32 + 16 + fr][fk];
        acc[0][0] = __builtin_amdgcn_mfma_f32_16x16x32_bf16(af0, bf0, acc[0][0], 0, 0, 0);
        acc[0][1] = __builtin_amdgcn_mfma_f32_16x16x32_bf16(af0, bf1, acc[0][1], 0, 0, 0);
        acc[1][0] = __builtin_amdgcn_mfma_f32_16x16x32_bf16(af1, bf0, acc[1][0], 0, 0, 0);
        acc[1][1] = __builtin_amdgcn_mfma_f32_16x16x32_bf16(af1, bf1, acc[1][1], 0, 0, 0);
    }
    // C/D layout (m89-verified): col = lane&15, row = (lane>>4)*4 + reg
    const int cr   = (lane >> 4) << 2;
    const int ccol = lane & 15;
    #pragma unroll
    for (int i = 0; i < 2; ++i)
        #pragma unroll
        for (int j = 0; j < 2; ++j) {
            int col = bn + wn * 32 + j * 16 + ccol;
            float bsv = bias[col];
            #pragma unroll
            for (int r = 0; r < 4; ++r) {
                int row = bm + wm * 32 + i * 16 + cr + r;
                float v = acc[i][j][r] + bsv;
                if (RESID) v += Rp[(size_t)row * N + col];
                if (RELU)  v = fmaxf(v, 0.f);
                if (OUT_BF16) ((unsigned short*)Cout)[(size_t)row * N + col] = f2b(v);
                else          ((float*)Cout)[(size_t)row * N + col] = v;
            }
        }
}

// ---------------- fused attention, one block per (b, h), bf16 I/O ----------
template<int CAUSAL>
__global__ __launch_bounds__(128) void attn_kernel(
        const unsigned short* __restrict__ Qp, int qs,
        const unsigned short* __restrict__ Kp,
        const unsigned short* __restrict__ Vp, int kvs,
        unsigned short* __restrict__ Op, int os)
{
    __shared__ float Ks[SEQ][DHEAD];
    __shared__ float Vs[SEQ][DHEAD];
    const int bh   = blockIdx.x;
    const int brow = (bh >> 3) * SEQ;
    const int hoff = (bh & 7) * DHEAD;
    const int t = threadIdx.x;
    #pragma unroll
    for (int it = 0; it < 8; ++it) {
        int idx  = it * 128 + t;      // 0..1023
        int srow = idx >> 3;          // 0..127
        int c8   = (idx & 7) << 3;    // 0..56
        uint4 ku = *(const uint4*)(Kp + (size_t)(brow + srow) * kvs + hoff + c8);
        uint4 vu = *(const uint4*)(Vp + (size_t)(brow + srow) * kvs + hoff + c8);
        unp8(ku, &Ks[srow][c8]);
        unp8(vu, &Vs[srow][c8]);
    }
    __syncthreads();
    float q[DHEAD];
    const unsigned short* qrow = Qp + (size_t)(brow + t) * qs + hoff;
    #pragma unroll
    for (int c8 = 0; c8 < DHEAD; c8 += 8)
        unp8(*(const uint4*)(qrow + c8), &q[c8]);
    float m = -INFINITY, l = 0.f;
    float acc[DHEAD];
    #pragma unroll
    for (int j = 0; j < DHEAD; ++j) acc[j] = 0.f;
    const int kend = CAUSAL ? (t + 1) : SEQ;
    for (int k = 0; k < kend; ++k) {
        float s = 0.f;
        const float4* kr = (const float4*)&Ks[k][0];
        #pragma unroll
        for (int j4 = 0; j4 < 16; ++j4) {
            float4 kv = kr[j4];
            s += q[j4*4+0]*kv.x + q[j4*4+1]*kv.y + q[j4*4+2]*kv.z + q[j4*4+3]*kv.w;
        }
        s *= 0.125f;
        float nm = fmaxf(m, s);
        float f = __expf(m - nm);
        float p = __expf(s - nm);
        l = l * f + p;
        const float4* vr = (const float4*)&Vs[k][0];
        #pragma unroll
        for (int j4 = 0; j4 < 16; ++j4) {
            float4 vv = vr[j4];
            acc[j4*4+0] = acc[j4*4+0] * f + p * vv.x;
            acc[j4*4+1] = acc[j4*4+1] * f + p * vv.y;
            acc[j4*4+2] = acc[j4*4+2] * f + p * vv.z;
            acc[j4*4+3] = acc[j4*4+3] * f + p * vv.w;
        }
        m = nm;
    }
    float invl = 1.f / l;
    unsigned short* orow = Op + (size_t)(brow + t) * os + hoff;
    #pragma unroll
    for (int j8 = 0; j8 < 8; ++j8) {
        uint4 o;
        o.x = (unsigned int)f2b(acc[j8*8+0]*invl) | ((unsigned int)f2b(acc[j8*8+1]*invl) << 16);
        o.y = (unsigned int)f2b(acc[j8*8+2]*invl) | ((unsigned int)f2b(acc[j8*8+3]*invl) << 16);
        o.z = (unsigned int)f2b(acc[j8*8+4]*invl) | ((unsigned int)f2b(acc[j8*8+5]*invl) << 16);
        o.w = (unsigned int)f2b(acc[j8*8+6]*invl) | ((unsigned int)f2b(acc[j8*8+7]*invl) << 16);
        *(uint4*)(orow + j8 * 8) = o;
    }
}

// ---------------------------------------------------------------------------
extern "C" void kernel_launch(void* const* d_in, const int* in_sizes, int n_in,
                              void* d_out, int out_size, void* d_ws, size_t ws_size,
                              hipStream_t stream)
{
    const int*   src       = (const int*)d_in[0];
    const int*   tgt       = (const int*)d_in[1];
    const float* src_emb   = (const float*)d_in[2];
    const float* tgt_emb   = (const float*)d_in[3];
    const float* enc_qkv_w = (const float*)d_in[4];
    const float* enc_qkv_b = (const float*)d_in[5];
    const float* enc_o_w   = (const float*)d_in[6];
    const float* enc_o_b   = (const float*)d_in[7];
    const float* enc_ff_w1 = (const float*)d_in[8];
    const float* enc_ff_b1 = (const float*)d_in[9];
    const float* enc_ff_w2 = (const float*)d_in[10];
    const float* enc_ff_b2 = (const float*)d_in[11];
    const float* enc_ln_g  = (const float*)d_in[12];
    const float* enc_ln_b  = (const float*)d_in[13];
    const float* enc_fg    = (const float*)d_in[14];
    const float* enc_fb    = (const float*)d_in[15];
    const float* dec_sqkv_w = (const float*)d_in[16];
    const float* dec_sqkv_b = (const float*)d_in[17];
    const float* dec_so_w   = (const float*)d_in[18];
    const float* dec_so_b   = (const float*)d_in[19];
    const float* dec_cqkv_w = (const float*)d_in[20];
    const float* dec_cqkv_b = (const float*)d_in[21];
    const float* dec_co_w   = (const float*)d_in[22];
    const float* dec_co_b   = (const float*)d_in[23];
    const float* dec_ff_w1  = (const float*)d_in[24];
    const float* dec_ff_b1  = (const float*)d_in[25];
    const float* dec_ff_w2  = (const float*)d_in[26];
    const float* dec_ff_b2  = (const float*)d_in[27];
    const float* dec_ln_g   = (const float*)d_in[28];
    const float* dec_ln_b   = (const float*)d_in[29];
    const float* dec_fg     = (const float*)d_in[30];
    const float* dec_fb     = (const float*)d_in[31];

    // ---- workspace carve (bf16 regions first; ~99 MB total) ----
    unsigned short* wp = (unsigned short*)d_ws;
    unsigned short* WencQKV  = wp; wp += (size_t)6 * 786432;   // [6][1536][512]
    unsigned short* WencO    = wp; wp += (size_t)6 * 262144;   // [6][512][512]
    unsigned short* WencF1   = wp; wp += (size_t)6 * 1048576;  // [6][2048][512]
    unsigned short* WencF2   = wp; wp += (size_t)6 * 1048576;  // [6][512][2048]
    unsigned short* WdecSQKV = wp; wp += (size_t)6 * 786432;
    unsigned short* WdecSO   = wp; wp += (size_t)6 * 262144;
    unsigned short* WdecCQKV = wp; wp += (size_t)6 * 786432;
    unsigned short* WdecCO   = wp; wp += (size_t)6 * 262144;
    unsigned short* WdecF1   = wp; wp += (size_t)6 * 1048576;
    unsigned short* WdecF2   = wp; wp += (size_t)6 * 1048576;
    unsigned short* Hb   = wp; wp += ROWS * D;        // LN out, bf16
    unsigned short* QKVb = wp; wp += ROWS * 3 * D;    // fused qkv out
    unsigned short* CQb  = wp; wp += ROWS * D;        // cross q
    unsigned short* CKVb = wp; wp += ROWS * 2 * D;    // cross k,v
    unsigned short* ATTb = wp; wp += ROWS * D;
    unsigned short* F1b  = wp; wp += ROWS * DFF;
    unsigned short* MEMb = wp; wp += ROWS * D;        // encoder memory, bf16
    float* X = (float*)wp;                            // fp32 residual stream

    // ---- weight conversion: fp32 [R][C] -> bf16 [C][R], batched ----
    auto T = [&](const float* in, unsigned short* out, int R_, int C_, int n) {
        transpose_cvt_kernel<<<dim3(C_ / 32, R_ / 32, n), 256, 0, stream>>>(in, out, R_, C_);
    };
    T(enc_qkv_w,  WencQKV,  512, 512, 18);
    T(enc_o_w,    WencO,    512, 512, 6);
    T(enc_ff_w1,  WencF1,   512, DFF, 6);
    T(enc_ff_w2,  WencF2,   DFF, 512, 6);
    T(dec_sqkv_w, WdecSQKV, 512, 512, 18);
    T(dec_so_w,   WdecSO,   512, 512, 6);
    T(dec_cqkv_w, WdecCQKV, 512, 512, 18);
    T(dec_co_w,   WdecCO,   512, 512, 6);
    T(dec_ff_w1,  WdecF1,   512, DFF, 6);
    T(dec_ff_w2,  WdecF2,   DFF, 512, 6);

    // ---------------- encoder ----------------
    embed_pe_kernel<<<2048, 256, 0, stream>>>(src, src_emb, X);
    for (int i = 0; i < LAYERS; ++i) {
        ln_kernel<1><<<256, 256, 0, stream>>>(X, enc_ln_g + (size_t)(i*2+0)*D, enc_ln_b + (size_t)(i*2+0)*D, Hb);
        mgemm_kernel<0,0,1><<<dim3(24,16), 256, 0, stream>>>(Hb, WencQKV + (size_t)i*786432,
                enc_qkv_b + (size_t)i*1536, nullptr, QKVb, 1536, 512);
        attn_kernel<0><<<64, 128, 0, stream>>>(QKVb, 1536, QKVb + 512, QKVb + 1024, 1536, ATTb, 512);
        mgemm_kernel<1,0,0><<<dim3(8,16), 256, 0, stream>>>(ATTb, WencO + (size_t)i*262144,
                enc_o_b + (size_t)i*512, X, X, 512, 512);
        ln_kernel<1><<<256, 256, 0, stream>>>(X, enc_ln_g + (size_t)(i*2+1)*D, enc_ln_b + (size_t)(i*2+1)*D, Hb);
        mgemm_kernel<0,1,1><<<dim3(32,16), 256, 0, stream>>>(Hb, WencF1 + (size_t)i*1048576,
                enc_ff_b1 + (size_t)i*DFF, nullptr, F1b, DFF, 512);
        mgemm_kernel<1,0,0><<<dim3(8,16), 256, 0, stream>>>(F1b, WencF2 + (size_t)i*1048576,
                enc_ff_b2 + (size_t)i*512, X, X, 512, DFF);
    }
    ln_kernel<1><<<256, 256, 0, stream>>>(X, enc_fg, enc_fb, MEMb);

    // ---------------- decoder ----------------
    embed_pe_kernel<<<2048, 256, 0, stream>>>(tgt, tgt_emb, X);
    for (int i = 0; i < LAYERS; ++i) {
        // self-attention (causal)
        ln_kernel<1><<<256, 256, 0, stream>>>(X, dec_ln_g + (size_t)(i*3+0)*D, dec_ln_b + (size_t)(i*3+0)*D, Hb);
        mgemm_kernel<0,0,1><<<dim3(24,16), 256, 0, stream>>>(Hb, WdecSQKV + (size_t)i*786432,
                dec_sqkv_b + (size_t)i*1536, nullptr, QKVb, 1536, 512);
        attn_kernel<1><<<64, 128, 0, stream>>>(QKVb, 1536, QKVb + 512, QKVb + 1024, 1536, ATTb, 512);
        mgemm_kernel<1,0,0><<<dim3(8,16), 256, 0, stream>>>(ATTb, WdecSO + (size_t)i*262144,
                dec_so_b + (size_t)i*512, X, X, 512, 512);
        // cross-attention
        ln_kernel<1><<<256, 256, 0, stream>>>(X, dec_ln_g + (size_t)(i*3+1)*D, dec_ln_b + (size_t)(i*3+1)*D, Hb);
        mgemm_kernel<0,0,1><<<dim3(8,16), 256, 0, stream>>>(Hb, WdecCQKV + (size_t)i*786432,
                dec_cqkv_b + (size_t)i*1536, nullptr, CQb, 512, 512);
        mgemm_kernel<0,0,1><<<dim3(16,16), 256, 0, stream>>>(MEMb, WdecCQKV + (size_t)i*786432 + 262144,
                dec_cqkv_b + (size_t)i*1536 + 512, nullptr, CKVb, 1024, 512);
        attn_kernel<0><<<64, 128, 0, stream>>>(CQb, 512, CKVb, CKVb + 512, 1024, ATTb, 512);
        mgemm_kernel<1,0,0><<<dim3(8,16), 256, 0, stream>>>(ATTb, WdecCO + (size_t)i*262144,
                dec_co_b + (size_t)i*512, X, X, 512, 512);
        // feed-forward
        ln_kernel<1><<<256, 256, 0, stream>>>(X, dec_ln_g + (size_t)(i*3+2)*D, dec_ln_b + (size_t)(i*3+2)*D, Hb);
        mgemm_kernel<0,1,1><<<dim3(32,16), 256, 0, stream>>>(Hb, WdecF1 + (size_t)i*1048576,
                dec_ff_b1 + (size_t)i*DFF, nullptr, F1b, DFF, 512);
        mgemm_kernel<1,0,0><<<dim3(8,16), 256, 0, stream>>>(F1b, WdecF2 + (size_t)i*1048576,
                dec_ff_b2 + (size_t)i*512, X, X, 512, DFF);
    }
    ln_kernel<0><<<256, 256, 0, stream>>>(X, dec_fg, dec_fb, d_out);
}

// Round 3
// 1118.079 us; speedup vs baseline: 5.3396x; 3.0752x over previous
//
#include <hip/hip_runtime.h>
#include <hip/hip_bf16.h>
#include <math.h>

#define D 512
#define NH 8
#define DHEAD 64
#define LAYERS 6
#define DFF 2048
#define BATCH 8
#define SEQ 128
#define ROWS (BATCH * SEQ)   // 1024

typedef float f32x4 __attribute__((ext_vector_type(4)));
typedef short bf16x8 __attribute__((ext_vector_type(8)));

__device__ __forceinline__ unsigned short f2b(float x) {
    return __builtin_bit_cast(unsigned short, __float2bfloat16(x));
}

// ---------------- embedding + positional encoding (fp32 out) ----------------
__global__ __launch_bounds__(256) void embed_pe_kernel(const int* __restrict__ tok,
        const float* __restrict__ emb, float* __restrict__ out)
{
    int i = blockIdx.x * 256 + threadIdx.x;
    int bs = i >> 9;
    int d  = i & 511;
    int s  = bs & (SEQ - 1);
    int tk = tok[bs];
    float dv  = expf(-(float)(d & ~1) * (9.210340371976184f / 512.0f));
    float arg = (float)s * dv;
    float pe  = (d & 1) ? cosf(arg) : sinf(arg);
    out[i] = emb[(size_t)tk * D + d] * 22.627416997969522f + pe;
}

// ---------------- batched transpose + fp32->bf16 convert --------------------
__global__ __launch_bounds__(256) void transpose_cvt_kernel(
        const float* __restrict__ in, unsigned short* __restrict__ out, int R, int C)
{
    __shared__ float t[32][33];
    const size_t moff = (size_t)blockIdx.z * R * C;
    const float* src = in + moff;
    unsigned short* dst = out + moff;
    const int r0 = blockIdx.y << 5, c0 = blockIdx.x << 5;
    const int tid = threadIdx.x;
    const int rr = tid >> 3, cc = (tid & 7) << 2;
    float4 v = *(const float4*)(src + (size_t)(r0 + rr) * C + c0 + cc);
    t[rr][cc] = v.x; t[rr][cc + 1] = v.y; t[rr][cc + 2] = v.z; t[rr][cc + 3] = v.w;
    __syncthreads();
    const int oc = tid >> 3, or4 = (tid & 7) << 2;
    ushort4 o;
    o.x = f2b(t[or4 + 0][oc]);
    o.y = f2b(t[or4 + 1][oc]);
    o.z = f2b(t[or4 + 2][oc]);
    o.w = f2b(t[or4 + 3][oc]);
    *(ushort4*)(dst + (size_t)(c0 + oc) * R + r0 + or4) = o;
}

// ---------------- LayerNorm: one wave per row of 512 ------------------------
template<int OUT_BF16>
__global__ __launch_bounds__(256) void ln_kernel(const float* __restrict__ x,
        const float* __restrict__ g, const float* __restrict__ bta,
        void* __restrict__ outp)
{
    int lane = threadIdx.x & 63;
    int row  = (blockIdx.x << 2) + (threadIdx.x >> 6);
    const float* xr = x + (size_t)row * D;
    int c = lane * 8;
    float4 v0 = *(const float4*)(xr + c);
    float4 v1 = *(const float4*)(xr + c + 4);
    float s  = v0.x + v0.y + v0.z + v0.w + v1.x + v1.y + v1.z + v1.w;
    float sq = v0.x*v0.x + v0.y*v0.y + v0.z*v0.z + v0.w*v0.w
             + v1.x*v1.x + v1.y*v1.y + v1.z*v1.z + v1.w*v1.w;
    #pragma unroll
    for (int o = 32; o; o >>= 1) {
        s  += __shfl_xor(s, o);
        sq += __shfl_xor(sq, o);
    }
    float mean = s * (1.0f / D);
    float var  = sq * (1.0f / D) - mean * mean;
    float inv  = rsqrtf(var + 1e-6f);
    float4 g0 = *(const float4*)(g + c),   g1 = *(const float4*)(g + c + 4);
    float4 b0 = *(const float4*)(bta + c), b1 = *(const float4*)(bta + c + 4);
    float4 o0, o1;
    o0.x = g0.x * (v0.x - mean) * inv + b0.x;
    o0.y = g0.y * (v0.y - mean) * inv + b0.y;
    o0.z = g0.z * (v0.z - mean) * inv + b0.z;
    o0.w = g0.w * (v0.w - mean) * inv + b0.w;
    o1.x = g1.x * (v1.x - mean) * inv + b1.x;
    o1.y = g1.y * (v1.y - mean) * inv + b1.y;
    o1.z = g1.z * (v1.z - mean) * inv + b1.z;
    o1.w = g1.w * (v1.w - mean) * inv + b1.w;
    if (OUT_BF16) {
        unsigned short* orow = (unsigned short*)outp + (size_t)row * D + c;
        uint4 o;
        o.x = (unsigned int)f2b(o0.x) | ((unsigned int)f2b(o0.y) << 16);
        o.y = (unsigned int)f2b(o0.z) | ((unsigned int)f2b(o0.w) << 16);
        o.z = (unsigned int)f2b(o1.x) | ((unsigned int)f2b(o1.y) << 16);
        o.w = (unsigned int)f2b(o1.z) | ((unsigned int)f2b(o1.w) << 16);
        *(uint4*)orow = o;
    } else {
        float* orow = (float*)outp + (size_t)row * D + c;
        *(float4*)(orow)     = o0;
        *(float4*)(orow + 4) = o1;
    }
}

// ---------------- bf16 MFMA GEMM: C = A[M,K] @ Wt[N,K]^T + bias -------------
template<int RESID, int RELU, int OUT_BF16>
__global__ __launch_bounds__(256) void mgemm_kernel(
        const unsigned short* __restrict__ A,   // bf16 [1024][K]
        const unsigned short* __restrict__ Wt,  // bf16 [N][K]
        const float* __restrict__ bias,         // fp32 [N]
        const float* __restrict__ Rp,           // fp32 [1024][N] residual
        void* __restrict__ Cout,                // bf16 or fp32 [1024][N]
        int N, int K)
{
    __shared__ unsigned short As[64][40];
    __shared__ unsigned short Bs[64][40];
    const int tid  = threadIdx.x;
    const int lane = tid & 63, wid = tid >> 6;
    const int wm = wid >> 1, wn = wid & 1;
    const int bm = blockIdx.y << 6, bn = blockIdx.x << 6;
    const int srow = tid >> 2, sk = (tid & 3) << 3;
    const unsigned short* Ag = A  + (size_t)(bm + srow) * K + sk;
    const unsigned short* Bg = Wt + (size_t)(bn + srow) * K + sk;
    const int fr = lane & 15;
    const int fk = (lane >> 4) << 3;
    f32x4 acc[2][2];
    #pragma unroll
    for (int i = 0; i < 2; ++i)
        #pragma unroll
        for (int j = 0; j < 2; ++j)
            acc[i][j] = (f32x4){0.f, 0.f, 0.f, 0.f};
    for (int k0 = 0; k0 < K; k0 += 32) {
        uint4 av = *(const uint4*)Ag;
        uint4 bv = *(const uint4*)Bg;
        Ag += 32; Bg += 32;
        __syncthreads();
        *(uint4*)&As[srow][sk] = av;
        *(uint4*)&Bs[srow][sk] = bv;
        __syncthreads();
        bf16x8 af0 = *(const bf16x8*)&As[wm * 32 + fr][fk];
        bf16x8 af1 = *(const bf16x8*)&As[wm * 32 + 16 + fr][fk];
        bf16x8 bf0 = *(const bf16x8*)&Bs[wn * 32 + fr][fk];
        bf16x8 bf1 = *(const bf16x8*)&Bs[wn * 32 + 16 + fr][fk];
        acc[0][0] = __builtin_amdgcn_mfma_f32_16x16x32_bf16(af0, bf0, acc[0][0], 0, 0, 0);
        acc[0][1] = __builtin_amdgcn_mfma_f32_16x16x32_bf16(af0, bf1, acc[0][1], 0, 0, 0);
        acc[1][0] = __builtin_amdgcn_mfma_f32_16x16x32_bf16(af1, bf0, acc[1][0], 0, 0, 0);
        acc[1][1] = __builtin_amdgcn_mfma_f32_16x16x32_bf16(af1, bf1, acc[1][1], 0, 0, 0);
    }
    const int cr   = (lane >> 4) << 2;
    const int ccol = lane & 15;
    #pragma unroll
    for (int i = 0; i < 2; ++i)
        #pragma unroll
        for (int j = 0; j < 2; ++j) {
            int col = bn + wn * 32 + j * 16 + ccol;
            float bsv = bias[col];
            #pragma unroll
            for (int r = 0; r < 4; ++r) {
                int row = bm + wm * 32 + i * 16 + cr + r;
                float v = acc[i][j][r] + bsv;
                if (RESID) v += Rp[(size_t)row * N + col];
                if (RELU)  v = fmaxf(v, 0.f);
                if (OUT_BF16) ((unsigned short*)Cout)[(size_t)row * N + col] = f2b(v);
                else          ((float*)Cout)[(size_t)row * N + col] = v;
            }
        }
}

// ---------------- MFMA flash-ish attention ----------------------------------
// Grid: 128 blocks = (b*8+h)*2 + qhalf. 256 threads = 4 waves x 16 q-rows.
// K [128][64] and Q-half [64][64] staged bf16 in LDS (pad to 72/row: 2-way
// bank = free). V staged transposed [64][136]. QK^T and PV via
// mfma_f32_16x16x32_bf16; softmax fully in registers (shfl_xor over the
// 16-lane column group); P written bf16 to wave-private LDS rows.
template<int CAUSAL>
__global__ __launch_bounds__(256) void attn_kernel(
        const unsigned short* __restrict__ Qp, int qs,
        const unsigned short* __restrict__ Kp,
        const unsigned short* __restrict__ Vp, int kvs,
        unsigned short* __restrict__ Op, int os)
{
    __shared__ unsigned short Ks[128 * 72];
    __shared__ unsigned short Qs[64 * 72];
    __shared__ unsigned short Vt[64 * 136];
    __shared__ unsigned short Ps[64 * 136];
    const int bh    = blockIdx.x >> 1;
    const int qbase = (blockIdx.x & 1) << 6;
    const int brow  = (bh >> 3) * SEQ;
    const int hoff  = (bh & 7) * DHEAD;
    const int tid = threadIdx.x, lane = tid & 63, wid = tid >> 6;

    // ---- stage K rows + V transposed ----
    #pragma unroll
    for (int it = 0; it < 4; ++it) {
        int idx = it * 256 + tid;          // 0..1023
        int row = idx >> 3;                // key 0..127
        int c8  = (idx & 7) << 3;          // d offset 0..56
        *(uint4*)&Ks[row * 72 + c8] =
            *(const uint4*)(Kp + (size_t)(brow + row) * kvs + hoff + c8);
        uint4 vu = *(const uint4*)(Vp + (size_t)(brow + row) * kvs + hoff + c8);
        unsigned arr[4] = {vu.x, vu.y, vu.z, vu.w};
        #pragma unroll
        for (int j = 0; j < 8; ++j)
            Vt[(c8 + j) * 136 + row] = (unsigned short)(arr[j >> 1] >> ((j & 1) * 16));
    }
    // ---- stage Q half ----
    #pragma unroll
    for (int it = 0; it < 2; ++it) {
        int idx = it * 256 + tid;          // 0..511
        int row = idx >> 3;                // 0..63
        int c8  = (idx & 7) << 3;
        *(uint4*)&Qs[row * 72 + c8] =
            *(const uint4*)(Qp + (size_t)(brow + qbase + row) * qs + hoff + c8);
    }
    __syncthreads();

    const int fr = lane & 15, fg = lane >> 4;
    // ---- QK^T: 16 q-rows x 128 keys per wave ----
    f32x4 accs[8];
    #pragma unroll
    for (int kf = 0; kf < 8; ++kf) accs[kf] = (f32x4){0.f, 0.f, 0.f, 0.f};
    bf16x8 aq0 = *(const bf16x8*)&Qs[(wid * 16 + fr) * 72 + fg * 8];
    bf16x8 aq1 = *(const bf16x8*)&Qs[(wid * 16 + fr) * 72 + 32 + fg * 8];
    #pragma unroll
    for (int kf = 0; kf < 8; ++kf) {
        bf16x8 bk0 = *(const bf16x8*)&Ks[(kf * 16 + fr) * 72 + fg * 8];
        bf16x8 bk1 = *(const bf16x8*)&Ks[(kf * 16 + fr) * 72 + 32 + fg * 8];
        accs[kf] = __builtin_amdgcn_mfma_f32_16x16x32_bf16(aq0, bk0, accs[kf], 0, 0, 0);
        accs[kf] = __builtin_amdgcn_mfma_f32_16x16x32_bf16(aq1, bk1, accs[kf], 0, 0, 0);
    }
    // ---- softmax (log2 domain): scale = 0.125 * log2(e) ----
    const float SC = 0.125f * 1.44269504f;
    float linv[4];
    #pragma unroll
    for (int r = 0; r < 4; ++r) {
        int qrow = qbase + wid * 16 + fg * 4 + r;     // global q row in [0,128)
        float sv[8];
        #pragma unroll
        for (int kf = 0; kf < 8; ++kf) {
            float s = accs[kf][r] * SC;
            if (CAUSAL) {
                int key = kf * 16 + fr;
                if (key > qrow) s = -1e30f;
            }
            sv[kf] = s;
        }
        float m = sv[0];
        #pragma unroll
        for (int kf = 1; kf < 8; ++kf) m = fmaxf(m, sv[kf]);
        #pragma unroll
        for (int o = 1; o < 16; o <<= 1) m = fmaxf(m, __shfl_xor(m, o));
        float l = 0.f;
        #pragma unroll
        for (int kf = 0; kf < 8; ++kf) {
            float p = exp2f(sv[kf] - m);
            l += p;
            Ps[(wid * 16 + fg * 4 + r) * 136 + kf * 16 + fr] = f2b(p);
        }
        #pragma unroll
        for (int o = 1; o < 16; o <<= 1) l += __shfl_xor(l, o);
        linv[r] = 1.f / l;
    }
    // ---- PV: P[16 rows][128] x V[128][64] ----
    f32x4 acco[4];
    #pragma unroll
    for (int df = 0; df < 4; ++df) acco[df] = (f32x4){0.f, 0.f, 0.f, 0.f};
    #pragma unroll
    for (int ks = 0; ks < 4; ++ks) {
        bf16x8 pa = *(const bf16x8*)&Ps[(wid * 16 + fr) * 136 + ks * 32 + fg * 8];
        #pragma unroll
        for (int df = 0; df < 4; ++df) {
            bf16x8 vb = *(const bf16x8*)&Vt[(df * 16 + fr) * 136 + ks * 32 + fg * 8];
            acco[df] = __builtin_amdgcn_mfma_f32_16x16x32_bf16(pa, vb, acco[df], 0, 0, 0);
        }
    }
    // ---- epilogue: normalize, store bf16 ----
    #pragma unroll
    for (int df = 0; df < 4; ++df)
        #pragma unroll
        for (int r = 0; r < 4; ++r) {
            int qrow = qbase + wid * 16 + fg * 4 + r;
            Op[(size_t)(brow + qrow) * os + hoff + df * 16 + fr] = f2b(acco[df][r] * linv[r]);
        }
}

// ---------------------------------------------------------------------------
extern "C" void kernel_launch(void* const* d_in, const int* in_sizes, int n_in,
                              void* d_out, int out_size, void* d_ws, size_t ws_size,
                              hipStream_t stream)
{
    const int*   src       = (const int*)d_in[0];
    const int*   tgt       = (const int*)d_in[1];
    const float* src_emb   = (const float*)d_in[2];
    const float* tgt_emb   = (const float*)d_in[3];
    const float* enc_qkv_w = (const float*)d_in[4];
    const float* enc_qkv_b = (const float*)d_in[5];
    const float* enc_o_w   = (const float*)d_in[6];
    const float* enc_o_b   = (const float*)d_in[7];
    const float* enc_ff_w1 = (const float*)d_in[8];
    const float* enc_ff_b1 = (const float*)d_in[9];
    const float* enc_ff_w2 = (const float*)d_in[10];
    const float* enc_ff_b2 = (const float*)d_in[11];
    const float* enc_ln_g  = (const float*)d_in[12];
    const float* enc_ln_b  = (const float*)d_in[13];
    const float* enc_fg    = (const float*)d_in[14];
    const float* enc_fb    = (const float*)d_in[15];
    const float* dec_sqkv_w = (const float*)d_in[16];
    const float* dec_sqkv_b = (const float*)d_in[17];
    const float* dec_so_w   = (const float*)d_in[18];
    const float* dec_so_b   = (const float*)d_in[19];
    const float* dec_cqkv_w = (const float*)d_in[20];
    const float* dec_cqkv_b = (const float*)d_in[21];
    const float* dec_co_w   = (const float*)d_in[22];
    const float* dec_co_b   = (const float*)d_in[23];
    const float* dec_ff_w1  = (const float*)d_in[24];
    const float* dec_ff_b1  = (const float*)d_in[25];
    const float* dec_ff_w2  = (const float*)d_in[26];
    const float* dec_ff_b2  = (const float*)d_in[27];
    const float* dec_ln_g   = (const float*)d_in[28];
    const float* dec_ln_b   = (const float*)d_in[29];
    const float* dec_fg     = (const float*)d_in[30];
    const float* dec_fb     = (const float*)d_in[31];

    // ---- workspace carve ----
    unsigned short* wp = (unsigned short*)d_ws;
    unsigned short* WencQKV  = wp; wp += (size_t)6 * 786432;
    unsigned short* WencO    = wp; wp += (size_t)6 * 262144;
    unsigned short* WencF1   = wp; wp += (size_t)6 * 1048576;
    unsigned short* WencF2   = wp; wp += (size_t)6 * 1048576;
    unsigned short* WdecSQKV = wp; wp += (size_t)6 * 786432;
    unsigned short* WdecSO   = wp; wp += (size_t)6 * 262144;
    unsigned short* WdecCQKV = wp; wp += (size_t)6 * 786432;
    unsigned short* WdecCO   = wp; wp += (size_t)6 * 262144;
    unsigned short* WdecF1   = wp; wp += (size_t)6 * 1048576;
    unsigned short* WdecF2   = wp; wp += (size_t)6 * 1048576;
    unsigned short* Hb   = wp; wp += ROWS * D;
    unsigned short* QKVb = wp; wp += ROWS * 3 * D;
    unsigned short* CQb  = wp; wp += ROWS * D;
    unsigned short* CKVb = wp; wp += ROWS * 2 * D;
    unsigned short* ATTb = wp; wp += ROWS * D;
    unsigned short* F1b  = wp; wp += ROWS * DFF;
    unsigned short* MEMb = wp; wp += ROWS * D;
    float* X = (float*)wp;

    // ---- weight conversion ----
    auto T = [&](const float* in, unsigned short* out, int R_, int C_, int n) {
        transpose_cvt_kernel<<<dim3(C_ / 32, R_ / 32, n), 256, 0, stream>>>(in, out, R_, C_);
    };
    T(enc_qkv_w,  WencQKV,  512, 512, 18);
    T(enc_o_w,    WencO,    512, 512, 6);
    T(enc_ff_w1,  WencF1,   512, DFF, 6);
    T(enc_ff_w2,  WencF2,   DFF, 512, 6);
    T(dec_sqkv_w, WdecSQKV, 512, 512, 18);
    T(dec_so_w,   WdecSO,   512, 512, 6);
    T(dec_cqkv_w, WdecCQKV, 512, 512, 18);
    T(dec_co_w,   WdecCO,   512, 512, 6);
    T(dec_ff_w1,  WdecF1,   512, DFF, 6);
    T(dec_ff_w2,  WdecF2,   DFF, 512, 6);

    // ---------------- encoder ----------------
    embed_pe_kernel<<<2048, 256, 0, stream>>>(src, src_emb, X);
    for (int i = 0; i < LAYERS; ++i) {
        ln_kernel<1><<<256, 256, 0, stream>>>(X, enc_ln_g + (size_t)(i*2+0)*D, enc_ln_b + (size_t)(i*2+0)*D, Hb);
        mgemm_kernel<0,0,1><<<dim3(24,16), 256, 0, stream>>>(Hb, WencQKV + (size_t)i*786432,
                enc_qkv_b + (size_t)i*1536, nullptr, QKVb, 1536, 512);
        attn_kernel<0><<<128, 256, 0, stream>>>(QKVb, 1536, QKVb + 512, QKVb + 1024, 1536, ATTb, 512);
        mgemm_kernel<1,0,0><<<dim3(8,16), 256, 0, stream>>>(ATTb, WencO + (size_t)i*262144,
                enc_o_b + (size_t)i*512, X, X, 512, 512);
        ln_kernel<1><<<256, 256, 0, stream>>>(X, enc_ln_g + (size_t)(i*2+1)*D, enc_ln_b + (size_t)(i*2+1)*D, Hb);
        mgemm_kernel<0,1,1><<<dim3(32,16), 256, 0, stream>>>(Hb, WencF1 + (size_t)i*1048576,
                enc_ff_b1 + (size_t)i*DFF, nullptr, F1b, DFF, 512);
        mgemm_kernel<1,0,0><<<dim3(8,16), 256, 0, stream>>>(F1b, WencF2 + (size_t)i*1048576,
                enc_ff_b2 + (size_t)i*512, X, X, 512, DFF);
    }
    ln_kernel<1><<<256, 256, 0, stream>>>(X, enc_fg, enc_fb, MEMb);

    // ---------------- decoder ----------------
    embed_pe_kernel<<<2048, 256, 0, stream>>>(tgt, tgt_emb, X);
    for (int i = 0; i < LAYERS; ++i) {
        ln_kernel<1><<<256, 256, 0, stream>>>(X, dec_ln_g + (size_t)(i*3+0)*D, dec_ln_b + (size_t)(i*3+0)*D, Hb);
        mgemm_kernel<0,0,1><<<dim3(24,16), 256, 0, stream>>>(Hb, WdecSQKV + (size_t)i*786432,
                dec_sqkv_b + (size_t)i*1536, nullptr, QKVb, 1536, 512);
        attn_kernel<1><<<128, 256, 0, stream>>>(QKVb, 1536, QKVb + 512, QKVb + 1024, 1536, ATTb, 512);
        mgemm_kernel<1,0,0><<<dim3(8,16), 256, 0, stream>>>(ATTb, WdecSO + (size_t)i*262144,
                dec_so_b + (size_t)i*512, X, X, 512, 512);
        ln_kernel<1><<<256, 256, 0, stream>>>(X, dec_ln_g + (size_t)(i*3+1)*D, dec_ln_b + (size_t)(i*3+1)*D, Hb);
        mgemm_kernel<0,0,1><<<dim3(8,16), 256, 0, stream>>>(Hb, WdecCQKV + (size_t)i*786432,
                dec_cqkv_b + (size_t)i*1536, nullptr, CQb, 512, 512);
        mgemm_kernel<0,0,1><<<dim3(16,16), 256, 0, stream>>>(MEMb, WdecCQKV + (size_t)i*786432 + 262144,
                dec_cqkv_b + (size_t)i*1536 + 512, nullptr, CKVb, 1024, 512);
        attn_kernel<0><<<128, 256, 0, stream>>>(CQb, 512, CKVb, CKVb + 512, 1024, ATTb, 512);
        mgemm_kernel<1,0,0><<<dim3(8,16), 256, 0, stream>>>(ATTb, WdecCO + (size_t)i*262144,
                dec_co_b + (size_t)i*512, X, X, 512, 512);
        ln_kernel<1><<<256, 256, 0, stream>>>(X, dec_ln_g + (size_t)(i*3+2)*D, dec_ln_b + (size_t)(i*3+2)*D, Hb);
        mgemm_kernel<0,1,1><<<dim3(32,16), 256, 0, stream>>>(Hb, WdecF1 + (size_t)i*1048576,
                dec_ff_b1 + (size_t)i*DFF, nullptr, F1b, DFF, 512);
        mgemm_kernel<1,0,0><<<dim3(8,16), 256, 0, stream>>>(F1b, WdecF2 + (size_t)i*1048576,
                dec_ff_b2 + (size_t)i*512, X, X, 512, DFF);
    }
    ln_kernel<0><<<256, 256, 0, stream>>>(X, dec_fg, dec_fb, d_out);
}

// Round 4
// 768.833 us; speedup vs baseline: 7.7652x; 1.4543x over previous
//
#include <hip/hip_runtime.h>
#include <hip/hip_bf16.h>
#include <math.h>

#define D 512
#define NH 8
#define DHEAD 64
#define LAYERS 6
#define DFF 2048
#define BATCH 8
#define SEQ 128
#define ROWS (BATCH * SEQ)   // 1024

typedef float f32x4 __attribute__((ext_vector_type(4)));
typedef short bf16x8 __attribute__((ext_vector_type(8)));

__device__ __forceinline__ unsigned short f2b(float x) {
    return __builtin_bit_cast(unsigned short, __float2bfloat16(x));
}

// ---------------- embedding + positional encoding (fp32 out) ----------------
__global__ __launch_bounds__(256) void embed_pe_kernel(const int* __restrict__ tok,
        const float* __restrict__ emb, float* __restrict__ out)
{
    int i = blockIdx.x * 256 + threadIdx.x;
    int bs = i >> 9;
    int d  = i & 511;
    int s  = bs & (SEQ - 1);
    int tk = tok[bs];
    float dv  = expf(-(float)(d & ~1) * (9.210340371976184f / 512.0f));
    float arg = (float)s * dv;
    float pe  = (d & 1) ? cosf(arg) : sinf(arg);
    out[i] = emb[(size_t)tk * D + d] * 22.627416997969522f + pe;
}

// ---------------- batched transpose + fp32->bf16 convert --------------------
__global__ __launch_bounds__(256) void transpose_cvt_kernel(
        const float* __restrict__ in, unsigned short* __restrict__ out, int R, int C)
{
    __shared__ float t[32][33];
    const size_t moff = (size_t)blockIdx.z * R * C;
    const float* src = in + moff;
    unsigned short* dst = out + moff;
    const int r0 = blockIdx.y << 5, c0 = blockIdx.x << 5;
    const int tid = threadIdx.x;
    const int rr = tid >> 3, cc = (tid & 7) << 2;
    float4 v = *(const float4*)(src + (size_t)(r0 + rr) * C + c0 + cc);
    t[rr][cc] = v.x; t[rr][cc + 1] = v.y; t[rr][cc + 2] = v.z; t[rr][cc + 3] = v.w;
    __syncthreads();
    const int oc = tid >> 3, or4 = (tid & 7) << 2;
    ushort4 o;
    o.x = f2b(t[or4 + 0][oc]);
    o.y = f2b(t[or4 + 1][oc]);
    o.z = f2b(t[or4 + 2][oc]);
    o.w = f2b(t[or4 + 3][oc]);
    *(ushort4*)(dst + (size_t)(c0 + oc) * R + r0 + or4) = o;
}

// ---------------- LayerNorm: one wave per row of 512 ------------------------
template<int OUT_BF16>
__global__ __launch_bounds__(256) void ln_kernel(const float* __restrict__ x,
        const float* __restrict__ g, const float* __restrict__ bta,
        void* __restrict__ outp)
{
    int lane = threadIdx.x & 63;
    int row  = (blockIdx.x << 2) + (threadIdx.x >> 6);
    const float* xr = x + (size_t)row * D;
    int c = lane * 8;
    float4 v0 = *(const float4*)(xr + c);
    float4 v1 = *(const float4*)(xr + c + 4);
    float s  = v0.x + v0.y + v0.z + v0.w + v1.x + v1.y + v1.z + v1.w;
    float sq = v0.x*v0.x + v0.y*v0.y + v0.z*v0.z + v0.w*v0.w
             + v1.x*v1.x + v1.y*v1.y + v1.z*v1.z + v1.w*v1.w;
    #pragma unroll
    for (int o = 32; o; o >>= 1) {
        s  += __shfl_xor(s, o);
        sq += __shfl_xor(sq, o);
    }
    float mean = s * (1.0f / D);
    float var  = sq * (1.0f / D) - mean * mean;
    float inv  = rsqrtf(var + 1e-6f);
    float4 g0 = *(const float4*)(g + c),   g1 = *(const float4*)(g + c + 4);
    float4 b0 = *(const float4*)(bta + c), b1 = *(const float4*)(bta + c + 4);
    float4 o0, o1;
    o0.x = g0.x * (v0.x - mean) * inv + b0.x;
    o0.y = g0.y * (v0.y - mean) * inv + b0.y;
    o0.z = g0.z * (v0.z - mean) * inv + b0.z;
    o0.w = g0.w * (v0.w - mean) * inv + b0.w;
    o1.x = g1.x * (v1.x - mean) * inv + b1.x;
    o1.y = g1.y * (v1.y - mean) * inv + b1.y;
    o1.z = g1.z * (v1.z - mean) * inv + b1.z;
    o1.w = g1.w * (v1.w - mean) * inv + b1.w;
    if (OUT_BF16) {
        unsigned short* orow = (unsigned short*)outp + (size_t)row * D + c;
        uint4 o;
        o.x = (unsigned int)f2b(o0.x) | ((unsigned int)f2b(o0.y) << 16);
        o.y = (unsigned int)f2b(o0.z) | ((unsigned int)f2b(o0.w) << 16);
        o.z = (unsigned int)f2b(o1.x) | ((unsigned int)f2b(o1.y) << 16);
        o.w = (unsigned int)f2b(o1.z) | ((unsigned int)f2b(o1.w) << 16);
        *(uint4*)orow = o;
    } else {
        float* orow = (float*)outp + (size_t)row * D + c;
        *(float4*)(orow)     = o0;
        *(float4*)(orow + 4) = o1;
    }
}

// ---------------- bf16 MFMA GEMM: C = A[M,K] @ Wt[N,K]^T + bias -------------
// BM=BN=64, BK=64, 256 threads = 4 waves in 2x2; each wave 2x2 frags of
// 16x16x32 over two k-subtiles (8 MFMA/wave/iter). Double-buffered LDS,
// reg-staged, ONE barrier per K-step; next tile's global loads issued before
// the barrier so they fly under compute. Optional z-batching via strides.
template<int RESID, int RELU, int OUT_BF16>
__global__ __launch_bounds__(256) void mgemm_kernel(
        const unsigned short* __restrict__ A,   // bf16 [1024][K]
        const unsigned short* __restrict__ Wt,  // bf16 [N][K]
        const float* __restrict__ bias,         // fp32 [N]
        const float* __restrict__ Rp,           // fp32 [1024][N] residual (z=0 only)
        void* __restrict__ Cout,                // bf16 or fp32 [1024][N]
        int N, int K,
        long aZ, long wZ, long bZ, long cZ)
{
    __shared__ unsigned short As[2][64][72];   // 144B row stride: 2-way bank = free
    __shared__ unsigned short Bs[2][64][72];
    const long z = blockIdx.z;
    const unsigned short* Ab = A  + z * aZ;
    const unsigned short* Wb = Wt + z * wZ;
    const float* biasb = bias + z * bZ;
    const int tid  = threadIdx.x;
    const int lane = tid & 63, wid = tid >> 6;
    const int wm = wid >> 1, wn = wid & 1;
    const int bm = blockIdx.y << 6, bn = blockIdx.x << 6;
    const int srow = tid >> 2, sk = (tid & 3) << 4;     // 32B (16 bf16) per thread
    const unsigned short* Ag = Ab + (size_t)(bm + srow) * K + sk;
    const unsigned short* Bg = Wb + (size_t)(bn + srow) * K + sk;
    const int fr = lane & 15;
    const int fk = (lane >> 4) << 3;
    f32x4 acc[2][2];
    #pragma unroll
    for (int i = 0; i < 2; ++i)
        #pragma unroll
        for (int j = 0; j < 2; ++j)
            acc[i][j] = (f32x4){0.f, 0.f, 0.f, 0.f};

    uint4 a0 = *(const uint4*)Ag, a1 = *(const uint4*)(Ag + 8);
    uint4 b0 = *(const uint4*)Bg, b1 = *(const uint4*)(Bg + 8);
    const int T = K >> 6;
    for (int t = 0; t < T; ++t) {
        const int p = t & 1;
        *(uint4*)&As[p][srow][sk]     = a0;
        *(uint4*)&As[p][srow][sk + 8] = a1;
        *(uint4*)&Bs[p][srow][sk]     = b0;
        *(uint4*)&Bs[p][srow][sk + 8] = b1;
        if (t + 1 < T) {
            Ag += 64; Bg += 64;
            a0 = *(const uint4*)Ag; a1 = *(const uint4*)(Ag + 8);
            b0 = *(const uint4*)Bg; b1 = *(const uint4*)(Bg + 8);
        }
        __syncthreads();
        #pragma unroll
        for (int s = 0; s < 2; ++s) {
            bf16x8 af0 = *(const bf16x8*)&As[p][wm * 32 + fr][s * 32 + fk];
            bf16x8 af1 = *(const bf16x8*)&As[p][wm * 32 + 16 + fr][s * 32 + fk];
            bf16x8 bf0 = *(const bf16x8*)&Bs[p][wn * 32 + fr][s * 32 + fk];
            bf16x8 bf1 = *(const bf16x8*)&Bs[p][wn * 32 + 16 + fr][s * 32 + fk];
            acc[0][0] = __builtin_amdgcn_mfma_f32_16x16x32_bf16(af0, bf0, acc[0][0], 0, 0, 0);
            acc[0][1] = __builtin_amdgcn_mfma_f32_16x16x32_bf16(af0, bf1, acc[0][1], 0, 0, 0);
            acc[1][0] = __builtin_amdgcn_mfma_f32_16x16x32_bf16(af1, bf0, acc[1][0], 0, 0, 0);
            acc[1][1] = __builtin_amdgcn_mfma_f32_16x16x32_bf16(af1, bf1, acc[1][1], 0, 0, 0);
        }
    }
    const int cr   = (lane >> 4) << 2;
    const int ccol = lane & 15;
    #pragma unroll
    for (int i = 0; i < 2; ++i)
        #pragma unroll
        for (int j = 0; j < 2; ++j) {
            int col = bn + wn * 32 + j * 16 + ccol;
            float bsv = biasb[col];
            #pragma unroll
            for (int r = 0; r < 4; ++r) {
                int row = bm + wm * 32 + i * 16 + cr + r;
                float v = acc[i][j][r] + bsv;
                if (RESID) v += Rp[(size_t)row * N + col];
                if (RELU)  v = fmaxf(v, 0.f);
                if (OUT_BF16) ((unsigned short*)Cout + z * cZ)[(size_t)row * N + col] = f2b(v);
                else          ((float*)Cout)[(size_t)row * N + col] = v;
            }
        }
}

// ---------------- MFMA flash-ish attention ----------------------------------
template<int CAUSAL>
__global__ __launch_bounds__(256) void attn_kernel(
        const unsigned short* __restrict__ Qp, int qs,
        const unsigned short* __restrict__ Kp,
        const unsigned short* __restrict__ Vp, int kvs,
        unsigned short* __restrict__ Op, int os)
{
    __shared__ unsigned short Ks[128 * 72];
    __shared__ unsigned short Qs[64 * 72];
    __shared__ unsigned short Vt[64 * 136];
    __shared__ unsigned short Ps[64 * 136];
    const int bh    = blockIdx.x >> 1;
    const int qbase = (blockIdx.x & 1) << 6;
    const int brow  = (bh >> 3) * SEQ;
    const int hoff  = (bh & 7) * DHEAD;
    const int tid = threadIdx.x, lane = tid & 63, wid = tid >> 6;

    #pragma unroll
    for (int it = 0; it < 4; ++it) {
        int idx = it * 256 + tid;
        int row = idx >> 3;
        int c8  = (idx & 7) << 3;
        *(uint4*)&Ks[row * 72 + c8] =
            *(const uint4*)(Kp + (size_t)(brow + row) * kvs + hoff + c8);
        uint4 vu = *(const uint4*)(Vp + (size_t)(brow + row) * kvs + hoff + c8);
        unsigned arr[4] = {vu.x, vu.y, vu.z, vu.w};
        #pragma unroll
        for (int j = 0; j < 8; ++j)
            Vt[(c8 + j) * 136 + row] = (unsigned short)(arr[j >> 1] >> ((j & 1) * 16));
    }
    #pragma unroll
    for (int it = 0; it < 2; ++it) {
        int idx = it * 256 + tid;
        int row = idx >> 3;
        int c8  = (idx & 7) << 3;
        *(uint4*)&Qs[row * 72 + c8] =
            *(const uint4*)(Qp + (size_t)(brow + qbase + row) * qs + hoff + c8);
    }
    __syncthreads();

    const int fr = lane & 15, fg = lane >> 4;
    f32x4 accs[8];
    #pragma unroll
    for (int kf = 0; kf < 8; ++kf) accs[kf] = (f32x4){0.f, 0.f, 0.f, 0.f};
    bf16x8 aq0 = *(const bf16x8*)&Qs[(wid * 16 + fr) * 72 + fg * 8];
    bf16x8 aq1 = *(const bf16x8*)&Qs[(wid * 16 + fr) * 72 + 32 + fg * 8];
    #pragma unroll
    for (int kf = 0; kf < 8; ++kf) {
        bf16x8 bk0 = *(const bf16x8*)&Ks[(kf * 16 + fr) * 72 + fg * 8];
        bf16x8 bk1 = *(const bf16x8*)&Ks[(kf * 16 + fr) * 72 + 32 + fg * 8];
        accs[kf] = __builtin_amdgcn_mfma_f32_16x16x32_bf16(aq0, bk0, accs[kf], 0, 0, 0);
        accs[kf] = __builtin_amdgcn_mfma_f32_16x16x32_bf16(aq1, bk1, accs[kf], 0, 0, 0);
    }
    const float SC = 0.125f * 1.44269504f;
    float linv[4];
    #pragma unroll
    for (int r = 0; r < 4; ++r) {
        int qrow = qbase + wid * 16 + fg * 4 + r;
        float sv[8];
        #pragma unroll
        for (int kf = 0; kf < 8; ++kf) {
            float s = accs[kf][r] * SC;
            if (CAUSAL) {
                int key = kf * 16 + fr;
                if (key > qrow) s = -1e30f;
            }
            sv[kf] = s;
        }
        float m = sv[0];
        #pragma unroll
        for (int kf = 1; kf < 8; ++kf) m = fmaxf(m, sv[kf]);
        #pragma unroll
        for (int o = 1; o < 16; o <<= 1) m = fmaxf(m, __shfl_xor(m, o));
        float l = 0.f;
        #pragma unroll
        for (int kf = 0; kf < 8; ++kf) {
            float p = exp2f(sv[kf] - m);
            l += p;
            Ps[(wid * 16 + fg * 4 + r) * 136 + kf * 16 + fr] = f2b(p);
        }
        #pragma unroll
        for (int o = 1; o < 16; o <<= 1) l += __shfl_xor(l, o);
        linv[r] = 1.f / l;
    }
    f32x4 acco[4];
    #pragma unroll
    for (int df = 0; df < 4; ++df) acco[df] = (f32x4){0.f, 0.f, 0.f, 0.f};
    #pragma unroll
    for (int ks = 0; ks < 4; ++ks) {
        bf16x8 pa = *(const bf16x8*)&Ps[(wid * 16 + fr) * 136 + ks * 32 + fg * 8];
        #pragma unroll
        for (int df = 0; df < 4; ++df) {
            bf16x8 vb = *(const bf16x8*)&Vt[(df * 16 + fr) * 136 + ks * 32 + fg * 8];
            acco[df] = __builtin_amdgcn_mfma_f32_16x16x32_bf16(pa, vb, acco[df], 0, 0, 0);
        }
    }
    #pragma unroll
    for (int df = 0; df < 4; ++df)
        #pragma unroll
        for (int r = 0; r < 4; ++r) {
            int qrow = qbase + wid * 16 + fg * 4 + r;
            Op[(size_t)(brow + qrow) * os + hoff + df * 16 + fr] = f2b(acco[df][r] * linv[r]);
        }
}

// ---------------------------------------------------------------------------
extern "C" void kernel_launch(void* const* d_in, const int* in_sizes, int n_in,
                              void* d_out, int out_size, void* d_ws, size_t ws_size,
                              hipStream_t stream)
{
    const int*   src       = (const int*)d_in[0];
    const int*   tgt       = (const int*)d_in[1];
    const float* src_emb   = (const float*)d_in[2];
    const float* tgt_emb   = (const float*)d_in[3];
    const float* enc_qkv_w = (const float*)d_in[4];
    const float* enc_qkv_b = (const float*)d_in[5];
    const float* enc_o_w   = (const float*)d_in[6];
    const float* enc_o_b   = (const float*)d_in[7];
    const float* enc_ff_w1 = (const float*)d_in[8];
    const float* enc_ff_b1 = (const float*)d_in[9];
    const float* enc_ff_w2 = (const float*)d_in[10];
    const float* enc_ff_b2 = (const float*)d_in[11];
    const float* enc_ln_g  = (const float*)d_in[12];
    const float* enc_ln_b  = (const float*)d_in[13];
    const float* enc_fg    = (const float*)d_in[14];
    const float* enc_fb    = (const float*)d_in[15];
    const float* dec_sqkv_w = (const float*)d_in[16];
    const float* dec_sqkv_b = (const float*)d_in[17];
    const float* dec_so_w   = (const float*)d_in[18];
    const float* dec_so_b   = (const float*)d_in[19];
    const float* dec_cqkv_w = (const float*)d_in[20];
    const float* dec_cqkv_b = (const float*)d_in[21];
    const float* dec_co_w   = (const float*)d_in[22];
    const float* dec_co_b   = (const float*)d_in[23];
    const float* dec_ff_w1  = (const float*)d_in[24];
    const float* dec_ff_b1  = (const float*)d_in[25];
    const float* dec_ff_w2  = (const float*)d_in[26];
    const float* dec_ff_b2  = (const float*)d_in[27];
    const float* dec_ln_g   = (const float*)d_in[28];
    const float* dec_ln_b   = (const float*)d_in[29];
    const float* dec_fg     = (const float*)d_in[30];
    const float* dec_fb     = (const float*)d_in[31];

    // ---- workspace carve ----
    unsigned short* wp = (unsigned short*)d_ws;
    unsigned short* WencQKV  = wp; wp += (size_t)6 * 786432;
    unsigned short* WencO    = wp; wp += (size_t)6 * 262144;
    unsigned short* WencF1   = wp; wp += (size_t)6 * 1048576;
    unsigned short* WencF2   = wp; wp += (size_t)6 * 1048576;
    unsigned short* WdecSQKV = wp; wp += (size_t)6 * 786432;
    unsigned short* WdecSO   = wp; wp += (size_t)6 * 262144;
    unsigned short* WdecCQKV = wp; wp += (size_t)6 * 786432;
    unsigned short* WdecCO   = wp; wp += (size_t)6 * 262144;
    unsigned short* WdecF1   = wp; wp += (size_t)6 * 1048576;
    unsigned short* WdecF2   = wp; wp += (size_t)6 * 1048576;
    unsigned short* Hb   = wp; wp += ROWS * D;
    unsigned short* QKVb = wp; wp += ROWS * 3 * D;
    unsigned short* CQb  = wp; wp += ROWS * D;
    unsigned short* CKVall = wp; wp += (size_t)6 * ROWS * 1024;  // [6][1024][1024]
    unsigned short* ATTb = wp; wp += ROWS * D;
    unsigned short* F1b  = wp; wp += ROWS * DFF;
    unsigned short* MEMb = wp; wp += ROWS * D;
    float* X = (float*)wp;

    // ---- weight conversion ----
    auto T = [&](const float* in, unsigned short* out, int R_, int C_, int n) {
        transpose_cvt_kernel<<<dim3(C_ / 32, R_ / 32, n), 256, 0, stream>>>(in, out, R_, C_);
    };
    T(enc_qkv_w,  WencQKV,  512, 512, 18);
    T(enc_o_w,    WencO,    512, 512, 6);
    T(enc_ff_w1,  WencF1,   512, DFF, 6);
    T(enc_ff_w2,  WencF2,   DFF, 512, 6);
    T(dec_sqkv_w, WdecSQKV, 512, 512, 18);
    T(dec_so_w,   WdecSO,   512, 512, 6);
    T(dec_cqkv_w, WdecCQKV, 512, 512, 18);
    T(dec_co_w,   WdecCO,   512, 512, 6);
    T(dec_ff_w1,  WdecF1,   512, DFF, 6);
    T(dec_ff_w2,  WdecF2,   DFF, 512, 6);

    // ---------------- encoder ----------------
    embed_pe_kernel<<<2048, 256, 0, stream>>>(src, src_emb, X);
    for (int i = 0; i < LAYERS; ++i) {
        ln_kernel<1><<<256, 256, 0, stream>>>(X, enc_ln_g + (size_t)(i*2+0)*D, enc_ln_b + (size_t)(i*2+0)*D, Hb);
        mgemm_kernel<0,0,1><<<dim3(24,16,1), 256, 0, stream>>>(Hb, WencQKV + (size_t)i*786432,
                enc_qkv_b + (size_t)i*1536, nullptr, QKVb, 1536, 512, 0, 0, 0, 0);
        attn_kernel<0><<<128, 256, 0, stream>>>(QKVb, 1536, QKVb + 512, QKVb + 1024, 1536, ATTb, 512);
        mgemm_kernel<1,0,0><<<dim3(8,16,1), 256, 0, stream>>>(ATTb, WencO + (size_t)i*262144,
                enc_o_b + (size_t)i*512, X, X, 512, 512, 0, 0, 0, 0);
        ln_kernel<1><<<256, 256, 0, stream>>>(X, enc_ln_g + (size_t)(i*2+1)*D, enc_ln_b + (size_t)(i*2+1)*D, Hb);
        mgemm_kernel<0,1,1><<<dim3(32,16,1), 256, 0, stream>>>(Hb, WencF1 + (size_t)i*1048576,
                enc_ff_b1 + (size_t)i*DFF, nullptr, F1b, DFF, 512, 0, 0, 0, 0);
        mgemm_kernel<1,0,0><<<dim3(8,16,1), 256, 0, stream>>>(F1b, WencF2 + (size_t)i*1048576,
                enc_ff_b2 + (size_t)i*512, X, X, 512, DFF, 0, 0, 0, 0);
    }
    ln_kernel<1><<<256, 256, 0, stream>>>(X, enc_fg, enc_fb, MEMb);

    // ---- all 6 decoder layers' cross K/V from memory: one batched GEMM ----
    mgemm_kernel<0,0,1><<<dim3(16,16,6), 256, 0, stream>>>(MEMb, WdecCQKV + 262144,
            dec_cqkv_b + 512, nullptr, CKVall, 1024, 512,
            0 /*aZ*/, 786432 /*wZ*/, 1536 /*bZ*/, (long)ROWS * 1024 /*cZ*/);

    // ---------------- decoder ----------------
    embed_pe_kernel<<<2048, 256, 0, stream>>>(tgt, tgt_emb, X);
    for (int i = 0; i < LAYERS; ++i) {
        ln_kernel<1><<<256, 256, 0, stream>>>(X, dec_ln_g + (size_t)(i*3+0)*D, dec_ln_b + (size_t)(i*3+0)*D, Hb);
        mgemm_kernel<0,0,1><<<dim3(24,16,1), 256, 0, stream>>>(Hb, WdecSQKV + (size_t)i*786432,
                dec_sqkv_b + (size_t)i*1536, nullptr, QKVb, 1536, 512, 0, 0, 0, 0);
        attn_kernel<1><<<128, 256, 0, stream>>>(QKVb, 1536, QKVb + 512, QKVb + 1024, 1536, ATTb, 512);
        mgemm_kernel<1,0,0><<<dim3(8,16,1), 256, 0, stream>>>(ATTb, WdecSO + (size_t)i*262144,
                dec_so_b + (size_t)i*512, X, X, 512, 512, 0, 0, 0, 0);
        ln_kernel<1><<<256, 256, 0, stream>>>(X, dec_ln_g + (size_t)(i*3+1)*D, dec_ln_b + (size_t)(i*3+1)*D, Hb);
        mgemm_kernel<0,0,1><<<dim3(8,16,1), 256, 0, stream>>>(Hb, WdecCQKV + (size_t)i*786432,
                dec_cqkv_b + (size_t)i*1536, nullptr, CQb, 512, 512, 0, 0, 0, 0);
        {
            const unsigned short* ckv = CKVall + (size_t)i * ROWS * 1024;
            attn_kernel<0><<<128, 256, 0, stream>>>(CQb, 512, ckv, ckv + 512, 1024, ATTb, 512);
        }
        mgemm_kernel<1,0,0><<<dim3(8,16,1), 256, 0, stream>>>(ATTb, WdecCO + (size_t)i*262144,
                dec_co_b + (size_t)i*512, X, X, 512, 512, 0, 0, 0, 0);
        ln_kernel<1><<<256, 256, 0, stream>>>(X, dec_ln_g + (size_t)(i*3+2)*D, dec_ln_b + (size_t)(i*3+2)*D, Hb);
        mgemm_kernel<0,1,1><<<dim3(32,16,1), 256, 0, stream>>>(Hb, WdecF1 + (size_t)i*1048576,
                dec_ff_b1 + (size_t)i*DFF, nullptr, F1b, DFF, 512, 0, 0, 0, 0);
        mgemm_kernel<1,0,0><<<dim3(8,16,1), 256, 0, stream>>>(F1b, WdecF2 + (size_t)i*1048576,
                dec_ff_b2 + (size_t)i*512, X, X, 512, DFF, 0, 0, 0, 0);
    }
    ln_kernel<0><<<256, 256, 0, stream>>>(X, dec_fg, dec_fb, d_out);
}